// Round 11
// baseline (344.515 us; speedup 1.0000x reference)
//
#include <hip/hip_runtime.h>

#define N_NODES  50000
#define N_EDGES  800000
#define HIDDEN   128
#define N_GRAPHS 256
#define N_CLASSES 10
#define WLD 136   // padded LDS leading dim for W tiles (4-bank shift/row -> 2-way max, free)

typedef short short8 __attribute__((ext_vector_type(8)));
typedef float floatx4 __attribute__((ext_vector_type(4)));

__device__ inline unsigned short bf16_rtne(float x) {
    unsigned u = __float_as_uint(x);
    unsigned r = ((u >> 16) & 1u) + 0x7fffu;
    return (unsigned short)((u + r) >> 16);
}

// ---------------- fused prep: count_pos (blocks 0..3124) | wsplit (3125..3252) | xconv (3253..6377) ----------------
__global__ void prep_kernel(const int* __restrict__ dst, int* __restrict__ deg, int* __restrict__ epos,
                            const float* __restrict__ W1, unsigned short* __restrict__ W1b,
                            const float* __restrict__ W2, unsigned short* __restrict__ W2b,
                            const float4* __restrict__ X, uint4* __restrict__ Xb,
                            int* __restrict__ counter) {
    int b = blockIdx.x;
    if (b < 3125) {                              // count_pos: 3125*256 == 800000 exact
        int e = b * 256 + threadIdx.x;
        epos[e] = atomicAdd(&deg[dst[e]], 1);
    } else if (b < 3253) {                       // wsplit: 128*256 == 32768 exact
        int idx = (b - 3125) * 256 + threadIdx.x;
        if (idx == 0) counter[0] = 0;
        int which = idx >> 14, sub = idx & (HIDDEN * HIDDEN - 1);
        int k = sub >> 7, n = sub & 127;
        (which ? W2b : W1b)[n * HIDDEN + k] = bf16_rtne((which ? W2 : W1)[sub]);
    } else {                                     // xconv: 3125*256 == 50000*16 exact
        int i = (b - 3253) * 256 + threadIdx.x;
        int n = i >> 4, c = i & 15;
        float4 a = X[(size_t)n * 32 + c * 2], v = X[(size_t)n * 32 + c * 2 + 1];
        uint4 o;
        o.x = (unsigned)bf16_rtne(a.x) | ((unsigned)bf16_rtne(a.y) << 16);
        o.y = (unsigned)bf16_rtne(a.z) | ((unsigned)bf16_rtne(a.w) << 16);
        o.z = (unsigned)bf16_rtne(v.x) | ((unsigned)bf16_rtne(v.y) << 16);
        o.w = (unsigned)bf16_rtne(v.z) | ((unsigned)bf16_rtne(v.w) << 16);
        Xb[(size_t)(c >> 2) * N_NODES * 4 + (size_t)n * 4 + (c & 3)] = o;
    }
}

__global__ void offsets_kernel(const int* __restrict__ deg, int* __restrict__ row_start,
                               int* __restrict__ counter) {
    int n = blockIdx.x * blockDim.x + threadIdx.x;
    int d = (n < N_NODES) ? deg[n] : 0;
    int lane = threadIdx.x & 63;
    int incl = d;
    #pragma unroll
    for (int off = 1; off < 64; off <<= 1) {
        int v = __shfl_up(incl, off, 64);
        if (lane >= off) incl += v;
    }
    int excl = incl - d;
    int total = __shfl(incl, 63, 64);
    int base = 0;
    if (lane == 0) base = atomicAdd(counter, total);
    base = __shfl(base, 0, 64);
    if (n < N_NODES) row_start[n] = base + excl;
}

__global__ void place_kernel(const int* __restrict__ src, const int* __restrict__ dst,
                             const int* __restrict__ epos, const int* __restrict__ row_start,
                             int* __restrict__ csr_src) {
    int e = blockIdx.x * blockDim.x + threadIdx.x;
    if (e >= N_EDGES) return;
    csr_src[row_start[dst[e]] + epos[e]] = src[e];
}

// ---------------- aggregation, XCD-sliced, sequential per-lane, 8-wide ILP ----------------
__device__ inline void acc_bf2(unsigned d, float& f0, float& f1) {
    f0 += __uint_as_float(d << 16);
    f1 += __uint_as_float(d & 0xffff0000u);
}
__device__ inline void acc8(const uint4 v, float* a) {
    acc_bf2(v.x, a[0], a[1]); acc_bf2(v.y, a[2], a[3]);
    acc_bf2(v.z, a[4], a[5]); acc_bf2(v.w, a[6], a[7]);
}

__global__ void agg_kernel(const uint4* __restrict__ Xb, const int* __restrict__ row_start,
                           const int* __restrict__ deg, const int* __restrict__ csr_src,
                           uint4* __restrict__ Tb /* row-major bf16 out */) {
    int s = blockIdx.x & 3;
    int n = (blockIdx.x >> 2) * 64 + (threadIdx.x >> 2);
    int chunk = threadIdx.x & 3;
    if (n >= N_NODES) return;
    const uint4* Ts = Xb + (size_t)s * (N_NODES * 4);
    float a[8];
    #pragma unroll
    for (int j = 0; j < 8; ++j) a[j] = 0.f;
    {   // self term
        uint4 v = Ts[(size_t)n * 4 + chunk];
        acc8(v, a);
    }
    int rs = row_start[n], d = deg[n];
    int i = 0;
    for (; i + 8 <= d; i += 8) {     // 8 independent load chains
        int s0 = csr_src[rs + i + 0];
        int s1 = csr_src[rs + i + 1];
        int s2 = csr_src[rs + i + 2];
        int s3 = csr_src[rs + i + 3];
        int s4 = csr_src[rs + i + 4];
        int s5 = csr_src[rs + i + 5];
        int s6 = csr_src[rs + i + 6];
        int s7 = csr_src[rs + i + 7];
        uint4 v0 = Ts[(size_t)s0 * 4 + chunk];
        uint4 v1 = Ts[(size_t)s1 * 4 + chunk];
        uint4 v2 = Ts[(size_t)s2 * 4 + chunk];
        uint4 v3 = Ts[(size_t)s3 * 4 + chunk];
        uint4 v4 = Ts[(size_t)s4 * 4 + chunk];
        uint4 v5 = Ts[(size_t)s5 * 4 + chunk];
        uint4 v6 = Ts[(size_t)s6 * 4 + chunk];
        uint4 v7 = Ts[(size_t)s7 * 4 + chunk];
        acc8(v0, a); acc8(v1, a); acc8(v2, a); acc8(v3, a);
        acc8(v4, a); acc8(v5, a); acc8(v6, a); acc8(v7, a);
    }
    for (; i + 2 <= d; i += 2) {
        int s0 = csr_src[rs + i + 0];
        int s1 = csr_src[rs + i + 1];
        uint4 v0 = Ts[(size_t)s0 * 4 + chunk];
        uint4 v1 = Ts[(size_t)s1 * 4 + chunk];
        acc8(v0, a); acc8(v1, a);
    }
    if (i < d) {
        int s0 = csr_src[rs + i];
        uint4 v0 = Ts[(size_t)s0 * 4 + chunk];
        acc8(v0, a);
    }
    uint4 o;
    o.x = (unsigned)bf16_rtne(a[0]) | ((unsigned)bf16_rtne(a[1]) << 16);
    o.y = (unsigned)bf16_rtne(a[2]) | ((unsigned)bf16_rtne(a[3]) << 16);
    o.z = (unsigned)bf16_rtne(a[4]) | ((unsigned)bf16_rtne(a[5]) << 16);
    o.w = (unsigned)bf16_rtne(a[6]) | ((unsigned)bf16_rtne(a[7]) << 16);
    Tb[(size_t)n * 16 + s * 4 + chunk] = o;
}

// ---------------- MFMA matmul, N-split, single-bf16 W: out = act(A @ W + b) ----------------
// blockIdx.y selects 64-col half; W^T rows staged in LDS (17.4 KB -> up to 8 blocks/CU).
__global__ __launch_bounds__(256)
void mm_mfma(const unsigned short* __restrict__ Ab,
             const unsigned short* __restrict__ Bw,
             const float* __restrict__ bias,
             unsigned short* __restrict__ Cb, int relu, int blocked) {
    __shared__ unsigned short WhS[64 * WLD];   // 17.4 KB

    int t = threadIdx.x;
    int col_base = blockIdx.y * 64;
    {   // stage W for 64 cols: 1024 ushort8, 4 per thread
        const short8* gh = (const short8*)(Bw + (size_t)col_base * HIDDEN);
        #pragma unroll
        for (int i = 0; i < 4; ++i) {
            int idx = i * 256 + t;              // 0..1023
            int row = idx >> 4, kk = (idx & 15) * 8;
            *(short8*)(WhS + row * WLD + kk) = gh[idx];
        }
    }
    __syncthreads();

    int w = t >> 6;
    int l = t & 63;
    int lane16 = l & 15;
    int quad = l >> 4;
    int row_base = blockIdx.x * 128 + w * 32;

    floatx4 acc[2][4];
    #pragma unroll
    for (int m = 0; m < 2; ++m)
        #pragma unroll
        for (int nt = 0; nt < 4; ++nt) acc[m][nt] = (floatx4){0.f, 0.f, 0.f, 0.f};

    #pragma unroll
    for (int kc = 0; kc < 4; ++kc) {
        int k0 = kc * 32 + quad * 8;
        short8 af[2];
        #pragma unroll
        for (int m = 0; m < 2; ++m) {
            int r = row_base + m * 16 + lane16;
            if (r < N_NODES) af[m] = *(const short8*)(Ab + (size_t)r * HIDDEN + k0);
            else             af[m] = (short8){0,0,0,0,0,0,0,0};
        }
        short8 bh[4];
        #pragma unroll
        for (int nt = 0; nt < 4; ++nt)
            bh[nt] = *(const short8*)(WhS + (nt * 16 + lane16) * WLD + k0);
        #pragma unroll
        for (int m = 0; m < 2; ++m)
            #pragma unroll
            for (int nt = 0; nt < 4; ++nt)
                acc[m][nt] = __builtin_amdgcn_mfma_f32_16x16x32_bf16(af[m], bh[nt], acc[m][nt], 0, 0, 0);
    }
    // epilogue: C/D layout col=lane16, row=quad*4+reg
    #pragma unroll
    for (int nt = 0; nt < 4; ++nt) {
        int col = col_base + nt * 16 + lane16;
        float b = bias[col];
        #pragma unroll
        for (int m = 0; m < 2; ++m) {
            #pragma unroll
            for (int reg = 0; reg < 4; ++reg) {
                int r = row_base + m * 16 + quad * 4 + reg;
                if (r < N_NODES) {
                    float o = acc[m][nt][reg] + b;
                    if (relu) o = fmaxf(o, 0.f);
                    size_t oi = blocked
                        ? ((size_t)(col >> 5) * N_NODES + r) * 32 + (col & 31)
                        : (size_t)r * HIDDEN + col;
                    Cb[oi] = bf16_rtne(o);
                }
            }
        }
    }
}

// ---------------- fused pool + mean + linear head (reads bf16 h) ----------------
__global__ void pool_head_kernel(const unsigned short* __restrict__ H, const int* __restrict__ batch,
                                 const float* __restrict__ Wl, const float* __restrict__ bl,
                                 float* __restrict__ out) {
    int g = blockIdx.x;
    int t = threadIdx.x;   // 256 threads
    __shared__ int bounds[2];
    __shared__ float acc2[2 * HIDDEN];
    __shared__ float mean[HIDDEN];

    if (t < 2) {
        int target = g + t;
        int lo = 0, hi = N_NODES;
        while (lo < hi) {
            int mid = (lo + hi) >> 1;
            if (batch[mid] < target) lo = mid + 1; else hi = mid;
        }
        bounds[t] = lo;
    }
    __syncthreads();
    int r0 = bounds[0], r1 = bounds[1];

    int c = t & 127, half = t >> 7;
    float s = 0.f;
    for (int r = r0 + half; r < r1; r += 2)
        s += __uint_as_float((unsigned)H[(size_t)r * HIDDEN + c] << 16);
    acc2[half * HIDDEN + c] = s;
    __syncthreads();
    if (t < HIDDEN) {
        float cntf = (float)(r1 - r0);
        mean[t] = (acc2[t] + acc2[HIDDEN + t]) / fmaxf(cntf, 1.0f);
    }
    __syncthreads();
    if (t < N_CLASSES) {
        float o = bl[t];
        #pragma unroll 8
        for (int k = 0; k < HIDDEN; ++k) o = fmaf(mean[k], Wl[k * N_CLASSES + t], o);
        out[(size_t)g * N_CLASSES + t] = o;
    }
}

extern "C" void kernel_launch(void* const* d_in, const int* in_sizes, int n_in,
                              void* d_out, int out_size, void* d_ws, size_t ws_size,
                              hipStream_t stream) {
    const float* x   = (const float*)d_in[0];
    const int*   ei  = (const int*)d_in[1];       // [2][N_EDGES]: row0=src, row1=dst
    const int*   bat = (const int*)d_in[2];
    const float* W1  = (const float*)d_in[3];
    const float* b1  = (const float*)d_in[4];
    const float* W2  = (const float*)d_in[5];
    const float* b2  = (const float*)d_in[6];
    const float* Wl  = (const float*)d_in[7];
    const float* bl  = (const float*)d_in[8];
    float* out = (float*)d_out;

    const int* src = ei;
    const int* dst = ei + N_EDGES;

    char* w = (char*)d_ws;
    size_t off = 0;
    auto alloc = [&](size_t bytes) { void* p = w + off; off = (off + bytes + 255) & ~(size_t)255; return p; };
    unsigned short* g_bf  = (unsigned short*)alloc((size_t)N_NODES * HIDDEN * 2);  // gather table (XCD-blocked)
    unsigned short* t_bf  = (unsigned short*)alloc((size_t)N_NODES * HIDDEN * 2);  // agg out / final h (row-major)
    unsigned short* z_bf  = (unsigned short*)alloc((size_t)N_NODES * HIDDEN * 2);  // mm1 out (row-major)
    int*   deg     = (int*)  alloc((size_t)N_NODES * 4);
    int*   rowst   = (int*)  alloc((size_t)N_NODES * 4);
    int*   epos    = (int*)  alloc((size_t)N_EDGES * 4);
    int*   csr_src = (int*)  alloc((size_t)N_EDGES * 4);
    int*   counter = (int*)  alloc(256);
    unsigned short* w1b = (unsigned short*)alloc((size_t)HIDDEN * HIDDEN * 2);
    unsigned short* w2b = (unsigned short*)alloc((size_t)HIDDEN * HIDDEN * 2);
    (void)ws_size; (void)in_sizes; (void)n_in; (void)out_size;

    hipMemsetAsync(deg, 0, (size_t)N_NODES * 4, stream);

    // fused prep: count_pos | wsplit(+counter init) | xconv  (6378 blocks)
    prep_kernel<<<6378, 256, 0, stream>>>(dst, deg, epos, W1, w1b, W2, w2b,
                                          (const float4*)x, (uint4*)g_bf, counter);
    offsets_kernel<<<(N_NODES + 255) / 256, 256, 0, stream>>>(deg, rowst, counter);
    place_kernel<<<(N_EDGES + 255) / 256, 256, 0, stream>>>(src, dst, epos, rowst, csr_src);

    const int agg_grid = 4 * ((N_NODES + 63) / 64);      // 4 slices x 782 blocks
    const dim3 mm_grid((N_NODES + 127) / 128, 2);        // 391 x 2 col-halves

    // layer 1
    agg_kernel<<<agg_grid, 256, 0, stream>>>((const uint4*)g_bf, rowst, deg, csr_src, (uint4*)t_bf);
    mm_mfma<<<mm_grid, 256, 0, stream>>>(t_bf, w1b, b1, z_bf, 1, 0);
    mm_mfma<<<mm_grid, 256, 0, stream>>>(z_bf, w2b, b2, g_bf, 1, 1);
    // layer 2
    agg_kernel<<<agg_grid, 256, 0, stream>>>((const uint4*)g_bf, rowst, deg, csr_src, (uint4*)t_bf);
    mm_mfma<<<mm_grid, 256, 0, stream>>>(t_bf, w1b, b1, z_bf, 1, 0);
    mm_mfma<<<mm_grid, 256, 0, stream>>>(z_bf, w2b, b2, g_bf, 1, 1);
    // layer 3 (no outer relu; row-major bf16 h into t_bf for pooling)
    agg_kernel<<<agg_grid, 256, 0, stream>>>((const uint4*)g_bf, rowst, deg, csr_src, (uint4*)t_bf);
    mm_mfma<<<mm_grid, 256, 0, stream>>>(t_bf, w1b, b1, z_bf, 1, 0);
    mm_mfma<<<mm_grid, 256, 0, stream>>>(z_bf, w2b, b2, t_bf, 0, 0);

    // fused mean-pool + head
    pool_head_kernel<<<N_GRAPHS, 256, 0, stream>>>(t_bf, bat, Wl, bl, out);
}